// Round 11
// baseline (430.849 us; speedup 1.0000x reference)
//
#include <hip/hip_runtime.h>

// BiLSTM: LSTM(B=2048,T=256,F=H=128) + linear head, fused, one block/CU.
// Round 11: TWO-QUAD OFFSET PIPELINE. Batches split into quad A (0-3) and
// quad B (4-7), each with a compact 4-row hbuf (4-way broadcast A-reads ->
// every lane owns exactly ONE element per quad). Pipeline stages offset by
// one window: even window = {h-MFMA quad A || GATE quad B}, odd window =
// {h-MFMA quad B || GATE quad A}. The MFMA chain and the GATE transcendental
// chain are data-independent in every window -> matrix and VALU pipes
// overlap instead of serializing (they measured 37%+39% sequential).
// gX (bias + x*w_ih) computed one group (2 steps) ahead in W2/W3, seeds the
// h-chain MFMA C; the step row is picked at extract time (D-row parity).
// Total MFMA and GATE work per step unchanged vs round 9.

typedef __attribute__((ext_vector_type(8))) short short8;
typedef __attribute__((ext_vector_type(4))) float f32x4;
typedef __attribute__((ext_vector_type(2))) float f32x2;

#define T_STEPS 256
#define L2E 1.4426950408889634f

__device__ __forceinline__ unsigned int cvt_pk_bf16(float lo, float hi) {
    unsigned int r;
    asm volatile("v_cvt_pk_bf16_f32 %0, %1, %2" : "=v"(r) : "v"(lo), "v"(hi));
    return r;
}
__device__ __forceinline__ unsigned short f2bf(float f) {
    unsigned int u = __builtin_bit_cast(unsigned int, f);
    u += 0x7fffu + ((u >> 16) & 1u);   // RNE
    return (unsigned short)(u >> 16);
}
__device__ __forceinline__ float rcp_fast(float x) { return __builtin_amdgcn_rcpf(x); }
__device__ __forceinline__ float exp2f_fast(float x) { return __builtin_amdgcn_exp2f(x); }
__device__ __forceinline__ f32x4 splat4(float v) { return (f32x4){v, v, v, v}; }

__device__ __forceinline__ short8 pack8(const f32x4 a, const f32x4 b) {
    short8 v;
    v[0] = (short)f2bf(a[0]); v[1] = (short)f2bf(a[1]);
    v[2] = (short)f2bf(a[2]); v[3] = (short)f2bf(a[3]);
    v[4] = (short)f2bf(b[0]); v[5] = (short)f2bf(b[1]);
    v[6] = (short)f2bf(b[2]); v[7] = (short)f2bf(b[3]);
    return v;
}

// barrier draining LDS only; VMEM prefetches stay in flight
#define LBAR() asm volatile("s_waitcnt lgkmcnt(0)\n\ts_barrier" ::: "memory")
#define MFMA16(A, B, C) __builtin_amdgcn_mfma_f32_16x16x32_bf16((A), (B), (C), 0, 0, 0)

// h-chain: CH[n] = (((SEED + af0*Bh0) + af1*Bh1) + af2*Bh2) + af3*Bh3
#define HCHAIN(CH, HB, SEED)                                                   \
  { short8 afh_[4];                                                            \
    _Pragma("unroll")                                                          \
    for (int kt = 0; kt < 4; ++kt)                                             \
      afh_[kt] = *reinterpret_cast<const short8*>(&(HB)[hr[kt]]);              \
    _Pragma("unroll")                                                          \
    for (int n = 0; n < 4; ++n) CH[n] = MFMA16(afh_[0], bq[4][n], SEED[n]);    \
    _Pragma("unroll")                                                          \
    for (int n = 0; n < 4; ++n) CH[n] = MFMA16(afh_[1], bq[5][n], CH[n]);      \
    _Pragma("unroll")                                                          \
    for (int n = 0; n < 4; ++n) CH[n] = MFMA16(afh_[2], bq[6][n], CH[n]);      \
    _Pragma("unroll")                                                          \
    for (int n = 0; n < 4; ++n) CH[n] = MFMA16(afh_[3], bq[7][n], CH[n]); }

// gates from 4 extracted scalars; 5 exp + 2 rcp
#define GATE(CHR, CS, WL, AJ, HU)                                              \
  { float gi = (CHR)[0], gf = (CHR)[1], gg = (CHR)[2], go = (CHR)[3];          \
    float ef = exp2f_fast(gf * L2E);                                           \
    float ei = exp2f_fast(gi * L2E);                                           \
    float eg = exp2f_fast(gg * (2.f * L2E));                                   \
    float Fq = ef + 1.f, Iq = ei + 1.f, Gq = eg + 1.f;                         \
    float pq = Iq * Gq;                                                        \
    float Rq = rcp_fast(Fq * pq);                                              \
    float cq = __builtin_fmaf(ef * pq, (CS), (ei * Fq) * (eg - 1.f)) * Rq;     \
    (CS) = cq;                                                                 \
    float ccq = fminf(fmaxf(cq, -15.f), 15.f);                                 \
    float eo = exp2f_fast(go * L2E);                                           \
    float ec = exp2f_fast(ccq * (2.f * L2E));                                  \
    float oh = (eo * (ec - 1.f)) * rcp_fast((eo + 1.f) * (ec + 1.f));          \
    (AJ) = __builtin_fmaf(oh, (WL), (AJ));                                     \
    (HU) = f2bf(oh); }

// One iter = 4 windows = one 2-step group (steps 2M, 2M+1) for each quad.
#define ITER(M, XR, XW, GXA, GXB, GXAN, GXBN)                                  \
  do {                                                                         \
    f32x4 ch[4];                                                               \
    /* ---- W0: A-MFMA(2M) || GATE_B(2M-1, r=1) ---- */                        \
    HCHAIN(ch, hbA, GXA);                                                      \
    { int tt = 2 * (M) + 4; if (tt >= T_STEPS) tt = 0;                         \
      f32x2 v = *reinterpret_cast<const f32x2*>(xrow + (size_t)tt * 128);      \
      nx0u = cvt_pk_bf16(v[0], v[1]); }                                        \
    { unsigned short hu; GATE(chBr, cstB, wlP, accB, hu); hbB[hw] = hu; }      \
    chAr[0] = ch[0][0]; chAr[1] = ch[1][0];                                    \
    chAr[2] = ch[2][0]; chAr[3] = ch[3][0];                                    \
    LBAR();                                                                    \
    /* ---- W1: B-MFMA(2M) || GATE_A(2M, r=0) ---- */                          \
    HCHAIN(ch, hbB, GXB);                                                      \
    { int tt = 2 * (M) + 5; if (tt >= T_STEPS) tt = 0;                         \
      f32x2 v = *reinterpret_cast<const f32x2*>(xrow + (size_t)tt * 128);      \
      nx1u = cvt_pk_bf16(v[0], v[1]); }                                        \
    { unsigned short hu; GATE(chAr, cstA, wl0, accA, hu); hbA[hw] = hu; }      \
    { int tw = 2 * (M) + 2; if (tw >= T_STEPS) tw = 0;                         \
      wlN0 = w_lin[tw * 128 + hid]; }                                          \
    chBr[0] = ch[0][0]; chBr[1] = ch[1][0];                                    \
    chBr[2] = ch[2][0]; chBr[3] = ch[3][0];                                    \
    LBAR();                                                                    \
    /* ---- W2: A-MFMA(2M+1) || GATE_B(2M, r=0) || x-MFMA kt01 ---- */         \
    HCHAIN(ch, hbA, GXA);                                                      \
    { short8 a0 = *reinterpret_cast<const short8*>(&xq[0][XR][xr[0]]);         \
      short8 a1 = *reinterpret_cast<const short8*>(&xq[0][XR][xr[1]]);         \
      short8 b0 = *reinterpret_cast<const short8*>(&xq[1][XR][xr[0]]);         \
      short8 b1 = *reinterpret_cast<const short8*>(&xq[1][XR][xr[1]]);         \
      _Pragma("unroll")                                                        \
      for (int n = 0; n < 4; ++n)                                              \
        GXAN[n] = MFMA16(a1, bq[1][n], MFMA16(a0, bq[0][n], splat4(bias[n]))); \
      _Pragma("unroll")                                                        \
      for (int n = 0; n < 4; ++n)                                              \
        GXBN[n] = MFMA16(b1, bq[1][n], MFMA16(b0, bq[0][n], splat4(bias[n]))); }\
    { unsigned short hu; GATE(chBr, cstB, wl0, accB, hu); hbB[hw] = hu; }      \
    { int tw = 2 * (M) + 3; if (tw >= T_STEPS) tw = 0;                         \
      wlN1 = w_lin[tw * 128 + hid]; }                                          \
    chAr[0] = ch[0][1]; chAr[1] = ch[1][1];                                    \
    chAr[2] = ch[2][1]; chAr[3] = ch[3][1];                                    \
    LBAR();                                                                    \
    /* ---- W3: B-MFMA(2M+1) || GATE_A(2M+1, r=1) || x kt23 || stage ---- */   \
    HCHAIN(ch, hbB, GXB);                                                      \
    { short8 a2 = *reinterpret_cast<const short8*>(&xq[0][XR][xr[2]]);         \
      short8 a3 = *reinterpret_cast<const short8*>(&xq[0][XR][xr[3]]);         \
      short8 b2 = *reinterpret_cast<const short8*>(&xq[1][XR][xr[2]]);         \
      short8 b3 = *reinterpret_cast<const short8*>(&xq[1][XR][xr[3]]);         \
      _Pragma("unroll")                                                        \
      for (int n = 0; n < 4; ++n)                                              \
        GXAN[n] = MFMA16(a3, bq[3][n], MFMA16(a2, bq[2][n], GXAN[n]));         \
      _Pragma("unroll")                                                        \
      for (int n = 0; n < 4; ++n)                                              \
        GXBN[n] = MFMA16(b3, bq[3][n], MFMA16(b2, bq[2][n], GXBN[n])); }       \
    *reinterpret_cast<unsigned int*>(&xq[qsel][XW][xw0]) = nx0u;               \
    *reinterpret_cast<unsigned int*>(&xq[qsel][XW][xw1]) = nx1u;               \
    { unsigned short hu; GATE(chAr, cstA, wl1, accA, hu); hbA[hw] = hu; }      \
    chBr[0] = ch[0][1]; chBr[1] = ch[1][1];                                    \
    chBr[2] = ch[2][1]; chBr[3] = ch[3][1];                                    \
    wlP = wl1; wl0 = wlN0; wl1 = wlN1;                                         \
    LBAR();                                                                    \
  } while (0)

__global__ __launch_bounds__(512, 2) void lstm_pipe_kernel(
    const float* __restrict__ x,     // [2048,256,128]
    const float* __restrict__ w_ih,  // [512,128]
    const float* __restrict__ w_hh,  // [512,128]
    const float* __restrict__ b_ih,  // [512]
    const float* __restrict__ b_hh,  // [512]
    const float* __restrict__ w_lin, // [1, 256*128]
    const float* __restrict__ b_lin, // [1]
    float* __restrict__ out)         // [2048]
{
    // xq[quad][group parity]: bf16 [16][128], row = 4*batchInQuad + step
    //   (rows ==2,3 mod 4 stay zero); col swizzle ^((row&7)<<3)
    // hb[quad]: compact bf16 [4][128], row = batchInQuad; col ^ (row<<3)
    __shared__ __align__(16) unsigned short xq[2][2][16 * 128];
    __shared__ __align__(16) unsigned short hb[2][4 * 128];
    __shared__ float redout[8][8];

    const int tid  = threadIdx.x;
    const int wave = tid >> 6;      // 0..7
    const int lane = tid & 63;
    const int c16  = lane & 15;
    const int kq   = lane >> 4;     // 0..3
    const int row0 = blockIdx.x * 8;
    const int hid  = wave * 16 + c16;
    const int qsel = wave >> 2;     // quad this wave stages x for

    unsigned short* hbA = hb[0];
    unsigned short* hbB = hb[1];

    // zero xq (16KB) + hb (2KB)
#pragma unroll
    for (int i = 0; i < 4; ++i)
        reinterpret_cast<unsigned long long*>(xq)[tid + 512 * i] = 0ull;
    if (tid < 256) reinterpret_cast<unsigned long long*>(hb)[tid] = 0ull;

    // ---- weights -> register B-fragments ----
    short8 bq[8][4];
#pragma unroll
    for (int kt = 0; kt < 8; ++kt) {
#pragma unroll
        for (int n = 0; n < 4; ++n) {
            const int G  = n * 128 + wave * 16 + c16;
            const int k0 = (kt & 3) * 32 + kq * 8;
            const float* src = (kt < 4) ? (w_ih + G * 128 + k0)
                                        : (w_hh + G * 128 + k0);
            f32x4 lo = *reinterpret_cast<const f32x4*>(src);
            f32x4 hi = *reinterpret_cast<const f32x4*>(src + 4);
            bq[kt][n] = pack8(lo, hi);
        }
    }
    float bias[4];
#pragma unroll
    for (int n = 0; n < 4; ++n) {
        const int G = n * 128 + wave * 16 + c16;
        bias[n] = b_ih[G] + b_hh[G];
    }

    // read indices: x A-row = c16; h A-row content = hb row c16>>2 (broadcast)
    int xr[4], hr[4];
    const int rr = c16 >> 2;
#pragma unroll
    for (int kt = 0; kt < 4; ++kt) {
        const int K = kt * 32 + kq * 8;
        xr[kt] = c16 * 128 + (K ^ ((c16 & 7) << 3));
        hr[kt] = rr * 128 + (K ^ (rr << 3));
    }
    // h write: lane (c16,kq) owns (batchInQuad kq, col hid) in both quads
    const int hw = kq * 128 + (hid ^ (kq << 3));
    // x staging rows: wave w stages its batch at rows 4*(w&3) + {0,1}
    const int xrw0 = 4 * (wave & 3);
    const int xrw1 = xrw0 + 1;
    const int xw0  = xrw0 * 128 + ((lane * 2) ^ ((xrw0 & 7) << 3));
    const int xw1  = xrw1 * 128 + ((lane * 2) ^ ((xrw1 & 7) << 3));
    const float* xrow = x + (size_t)(row0 + wave) * T_STEPS * 128 + lane * 2;

    __syncthreads();  // zeros visible before staging

    // stage groups 0 (t=0,1) and 1 (t=2,3)
#pragma unroll
    for (int g = 0; g < 2; ++g) {
        f32x2 v0 = *reinterpret_cast<const f32x2*>(xrow + (size_t)(2 * g) * 128);
        f32x2 v1 = *reinterpret_cast<const f32x2*>(xrow + (size_t)(2 * g + 1) * 128);
        *reinterpret_cast<unsigned int*>(&xq[qsel][g][xw0]) = cvt_pk_bf16(v0[0], v0[1]);
        *reinterpret_cast<unsigned int*>(&xq[qsel][g][xw1]) = cvt_pk_bf16(v1[0], v1[1]);
    }
    __syncthreads();

    // gX(group 0) for both quads
    f32x4 gxa[4], gxb[4], gxa2[4], gxb2[4];
    {
        short8 a0 = *reinterpret_cast<const short8*>(&xq[0][0][xr[0]]);
        short8 a1 = *reinterpret_cast<const short8*>(&xq[0][0][xr[1]]);
        short8 a2 = *reinterpret_cast<const short8*>(&xq[0][0][xr[2]]);
        short8 a3 = *reinterpret_cast<const short8*>(&xq[0][0][xr[3]]);
        short8 b0 = *reinterpret_cast<const short8*>(&xq[1][0][xr[0]]);
        short8 b1 = *reinterpret_cast<const short8*>(&xq[1][0][xr[1]]);
        short8 b2 = *reinterpret_cast<const short8*>(&xq[1][0][xr[2]]);
        short8 b3 = *reinterpret_cast<const short8*>(&xq[1][0][xr[3]]);
#pragma unroll
        for (int n = 0; n < 4; ++n) {
            gxa[n] = MFMA16(a3, bq[3][n], MFMA16(a2, bq[2][n],
                     MFMA16(a1, bq[1][n], MFMA16(a0, bq[0][n], splat4(bias[n])))));
            gxb[n] = MFMA16(b3, bq[3][n], MFMA16(b2, bq[2][n],
                     MFMA16(b1, bq[1][n], MFMA16(b0, bq[0][n], splat4(bias[n])))));
        }
    }

    float cstA = 0.f, cstB = 0.f, accA = 0.f, accB = 0.f;
    float chAr[4] = {0.f, 0.f, 0.f, 0.f};
    float chBr[4] = {0.f, 0.f, 0.f, 0.f};  // fake GATE_B(-1) -> h = 0
    float wlP = 0.f;
    float wl0 = w_lin[hid];
    float wl1 = w_lin[128 + hid];
    float wlN0 = 0.f, wlN1 = 0.f;
    unsigned int nx0u = 0u, nx1u = 0u;

    LBAR();

    for (int m = 0; m < 128; m += 2) {
        ITER(m,     1, 0, gxa, gxb, gxa2, gxb2);
        ITER(m + 1, 0, 1, gxa2, gxb2, gxa, gxb);
    }

    // epilogue: GATE_B(255) (r=1 extract already in chBr)
    { unsigned short hu; GATE(chBr, cstB, wlP, accB, hu); (void)hu; }

    // ---- reduce: accA -> batch kq (quad A), accB -> batch 4+kq ----
#pragma unroll
    for (int r = 0; r < 2; ++r) {
        float v = (r == 0) ? accA : accB;
        v += __shfl_xor(v, 1);
        v += __shfl_xor(v, 2);
        v += __shfl_xor(v, 4);
        v += __shfl_xor(v, 8);
        if (c16 == 0) redout[wave][r * 4 + kq] = v;
    }
    __syncthreads();
    if (tid < 8) {
        float s = b_lin[0];
#pragma unroll
        for (int w = 0; w < 8; ++w) s += redout[w][tid];
        out[row0 + tid] = s;
    }
}

extern "C" void kernel_launch(void* const* d_in, const int* in_sizes, int n_in,
                              void* d_out, int out_size, void* d_ws, size_t ws_size,
                              hipStream_t stream) {
    const float* x     = (const float*)d_in[0];
    const float* w_ih  = (const float*)d_in[1];
    const float* w_hh  = (const float*)d_in[2];
    const float* b_ih  = (const float*)d_in[3];
    const float* b_hh  = (const float*)d_in[4];
    const float* w_lin = (const float*)d_in[5];
    const float* b_lin = (const float*)d_in[6];
    float* out = (float*)d_out;

    lstm_pipe_kernel<<<256, 512, 0, stream>>>(x, w_ih, w_hh, b_ih, b_hh, w_lin, b_lin, out);
}

// Round 12
// 214.009 us; speedup vs baseline: 2.0132x; 2.0132x over previous
//
#include <hip/hip_runtime.h>

// BiLSTM: LSTM(B=2048,T=256,F=H=128) + linear head, fused, one block/CU.
// FINAL (champion = round 5, 197.7 us): compact 8-row hbuf (2KB) — lane
// pairs (c16, c16|2) read the SAME address (broadcast, free) so distinct
// h-read traffic halves; h-writes bank-conflict-free under the ^(row<<3)
// swizzle. Fused triple-rcp gate math (7 trans/element). x-matmul batched
// over 2 timesteps; light lgkmcnt-only barriers (1/step).
//
// Structural floor rationale (rounds 3-11): three spill-free schedules
// converge at ~1850 cy/step, pipes each ~37-46% busy, latency-bound on the
// serial chain (barrier -> h ds_read -> 4-dep MFMA -> trans gate chain ->
// h write). More waves/SIMD or more pipeline state spills (weights are a
// mandatory 128 VGPR/wave -> 2 waves/SIMD tier); redundant-MFMA overlap
// streams are net losses.

typedef __attribute__((ext_vector_type(8))) short short8;
typedef __attribute__((ext_vector_type(4))) float f32x4;
typedef __attribute__((ext_vector_type(2))) float f32x2;
typedef __attribute__((ext_vector_type(2))) unsigned long long u64x2;

#define T_STEPS 256
#define L2E 1.4426950408889634f

__device__ __forceinline__ unsigned int cvt_pk_bf16(float lo, float hi) {
    unsigned int r;
    asm volatile("v_cvt_pk_bf16_f32 %0, %1, %2" : "=v"(r) : "v"(lo), "v"(hi));
    return r;
}
__device__ __forceinline__ unsigned short f2bf(float f) {
    unsigned int u = __builtin_bit_cast(unsigned int, f);
    u += 0x7fffu + ((u >> 16) & 1u);   // RNE
    return (unsigned short)(u >> 16);
}
__device__ __forceinline__ float rcp_fast(float x) { return __builtin_amdgcn_rcpf(x); }
__device__ __forceinline__ float exp2f_fast(float x) { return __builtin_amdgcn_exp2f(x); }

__device__ __forceinline__ short8 pack8(const f32x4 a, const f32x4 b) {
    short8 v;
    v[0] = (short)f2bf(a[0]); v[1] = (short)f2bf(a[1]);
    v[2] = (short)f2bf(a[2]); v[3] = (short)f2bf(a[3]);
    v[4] = (short)f2bf(b[0]); v[5] = (short)f2bf(b[1]);
    v[6] = (short)f2bf(b[2]); v[7] = (short)f2bf(b[3]);
    return v;
}

// barrier that drains LDS ops only; VMEM prefetches stay in flight
#define LBAR() asm volatile("s_waitcnt lgkmcnt(0)\n\ts_barrier" ::: "memory")

// elementwise for sub-step S (0/1): gates = gX[][2S+j] + gh0[][j] + gh1[][j]
// c' = [ef*I*G*c + ei*(eg-1)*F] * rcp(F*I*G)
#define ELEM(S, WL, WR)                                                        \
  do {                                                                         \
    float oh0_, oh1_;                                                          \
    _Pragma("unroll")                                                          \
    for (int j = 0; j < 2; ++j) {                                              \
      float gi = gX[0][2*(S)+j] + gh0[0][j] + gh1[0][j];                       \
      float gf = gX[1][2*(S)+j] + gh0[1][j] + gh1[1][j];                       \
      float gg = gX[2][2*(S)+j] + gh0[2][j] + gh1[2][j];                       \
      float go = gX[3][2*(S)+j] + gh0[3][j] + gh1[3][j];                       \
      float ef = exp2f_fast(gf * L2E);                                         \
      float ei = exp2f_fast(gi * L2E);                                         \
      float eg = exp2f_fast(gg * (2.f * L2E));                                 \
      float F = ef + 1.f, I = ei + 1.f, G = eg + 1.f;                          \
      float p  = I * G;                                                        \
      float R  = rcp_fast(F * p);                                              \
      float t1 = ef * p;                                                       \
      float t4 = (ei * F) * (eg - 1.f);                                        \
      float c  = __builtin_fmaf(t1, cstate[j], t4) * R;                        \
      cstate[j] = c;                                                           \
      float cc = fminf(fmaxf(c, -15.f), 15.f);                                 \
      float eo = exp2f_fast(go * L2E);                                         \
      float ec = exp2f_fast(cc * (2.f * L2E));                                 \
      float oh = (eo * (ec - 1.f)) * rcp_fast((eo + 1.f) * (ec + 1.f));        \
      accout[j] = __builtin_fmaf(oh, (WL), accout[j]);                         \
      if (j == 0) oh0_ = oh; else oh1_ = oh;                                   \
    }                                                                          \
    unsigned int pk_ = cvt_pk_bf16(oh0_, oh1_);                                \
    hbuf[WR][hwidx0] = (unsigned short)pk_;                                    \
    hbuf[WR][hwidx1] = (unsigned short)(pk_ >> 16);                            \
  } while (0)

// one 2-step group starting at even T0; XP = xbuf parity of this group
#define GROUP(T0, XP)                                                          \
  do {                                                                         \
    short8 afh[4], afx[4];                                                     \
    _Pragma("unroll")                                                          \
    for (int kt = 0; kt < 4; ++kt) {                                           \
      int idxh = (hcr * 128 + kt * 32 + kq * 8) ^ (hcr << 3);                  \
      afh[kt] = *reinterpret_cast<const short8*>(&hbuf[0][idxh]);              \
    }                                                                          \
    _Pragma("unroll")                                                          \
    for (int kt = 0; kt < 4; ++kt) {                                           \
      int idx = (c16 * 128 + kt * 32 + kq * 8) ^ ((c16 & 7) << 3);             \
      afx[kt] = *reinterpret_cast<const short8*>(&xbuf[XP][idx]);              \
    }                                                                          \
    /* prefetch next group's x + w_lin */                                      \
    {                                                                          \
      const int tt = ((T0) + 2 < T_STEPS) ? (T0) + 2 : 0;                      \
      nx0 = *reinterpret_cast<const f32x2*>(xrow + (size_t)tt * 128);          \
      nx1 = *reinterpret_cast<const f32x2*>(xrow + (size_t)(tt + 1) * 128);    \
      wlA2 = w_lin[tt * 128 + hid];                                            \
      wlB2 = w_lin[(tt + 1) * 128 + hid];                                      \
    }                                                                          \
    f32x4 gX[4], gh0[4], gh1[4];                                               \
    _Pragma("unroll")                                                          \
    for (int n = 0; n < 4; ++n) {                                              \
      gX[n] = (f32x4){bias[n], bias[n], bias[n], bias[n]};                     \
      gh0[n] = (f32x4){0.f, 0.f, 0.f, 0.f};                                    \
      gh1[n] = (f32x4){0.f, 0.f, 0.f, 0.f};                                    \
    }                                                                          \
    _Pragma("unroll")                                                          \
    for (int n = 0; n < 4; ++n) {                                              \
      gh0[n] = __builtin_amdgcn_mfma_f32_16x16x32_bf16(afh[0], bq[4][n], gh0[n], 0, 0, 0); \
      gh1[n] = __builtin_amdgcn_mfma_f32_16x16x32_bf16(afh[2], bq[6][n], gh1[n], 0, 0, 0); \
    }                                                                          \
    _Pragma("unroll")                                                          \
    for (int n = 0; n < 4; ++n) {                                              \
      gh0[n] = __builtin_amdgcn_mfma_f32_16x16x32_bf16(afh[1], bq[5][n], gh0[n], 0, 0, 0); \
      gh1[n] = __builtin_amdgcn_mfma_f32_16x16x32_bf16(afh[3], bq[7][n], gh1[n], 0, 0, 0); \
    }                                                                          \
    _Pragma("unroll")                                                          \
    for (int kt = 0; kt < 4; ++kt)                                             \
      _Pragma("unroll")                                                        \
      for (int n = 0; n < 4; ++n)                                              \
        gX[n] = __builtin_amdgcn_mfma_f32_16x16x32_bf16(afx[kt], bq[kt][n], gX[n], 0, 0, 0); \
    ELEM(0, wlA, 1);                                                           \
    LBAR();                                                                    \
    /* ---- step B (s=1) ---- */                                               \
    _Pragma("unroll")                                                          \
    for (int kt = 0; kt < 4; ++kt) {                                           \
      int idxh = (hcr * 128 + kt * 32 + kq * 8) ^ (hcr << 3);                  \
      afh[kt] = *reinterpret_cast<const short8*>(&hbuf[1][idxh]);              \
    }                                                                          \
    _Pragma("unroll")                                                          \
    for (int n = 0; n < 4; ++n) {                                              \
      gh0[n] = (f32x4){0.f, 0.f, 0.f, 0.f};                                    \
      gh1[n] = (f32x4){0.f, 0.f, 0.f, 0.f};                                    \
    }                                                                          \
    _Pragma("unroll")                                                          \
    for (int n = 0; n < 4; ++n) {                                              \
      gh0[n] = __builtin_amdgcn_mfma_f32_16x16x32_bf16(afh[0], bq[4][n], gh0[n], 0, 0, 0); \
      gh1[n] = __builtin_amdgcn_mfma_f32_16x16x32_bf16(afh[2], bq[6][n], gh1[n], 0, 0, 0); \
    }                                                                          \
    _Pragma("unroll")                                                          \
    for (int n = 0; n < 4; ++n) {                                              \
      gh0[n] = __builtin_amdgcn_mfma_f32_16x16x32_bf16(afh[1], bq[5][n], gh0[n], 0, 0, 0); \
      gh1[n] = __builtin_amdgcn_mfma_f32_16x16x32_bf16(afh[3], bq[7][n], gh1[n], 0, 0, 0); \
    }                                                                          \
    /* stage next group's x into the other xbuf */                             \
    {                                                                          \
      unsigned int p0 = cvt_pk_bf16(nx0[0], nx0[1]);                           \
      unsigned int p1 = cvt_pk_bf16(nx1[0], nx1[1]);                           \
      *reinterpret_cast<unsigned int*>(&xbuf[(XP) ^ 1][xwidx0]) = p0;          \
      *reinterpret_cast<unsigned int*>(&xbuf[(XP) ^ 1][xwidx1]) = p1;          \
    }                                                                          \
    ELEM(1, wlB, 0);                                                           \
    wlA = wlA2; wlB = wlB2;                                                    \
    LBAR();                                                                    \
  } while (0)

__global__ __launch_bounds__(512, 2) void lstm_fused_kernel(
    const float* __restrict__ x,     // [2048,256,128]
    const float* __restrict__ w_ih,  // [512,128]
    const float* __restrict__ w_hh,  // [512,128]
    const float* __restrict__ b_ih,  // [512]
    const float* __restrict__ b_hh,  // [512]
    const float* __restrict__ w_lin, // [1, 256*128]
    const float* __restrict__ b_lin, // [1]
    float* __restrict__ out)         // [2048]
{
    // xbuf: bf16 [16 rows][128 k], swizzle ^((row&7)<<3)  (8 batch x 2 steps)
    // hbuf: COMPACT bf16 [8 rows][128 k], swizzle ^(row<<3); row == batch row
    __shared__ __align__(16) unsigned short xbuf[2][16 * 128];
    __shared__ __align__(16) unsigned short hbuf[2][8 * 128];
    __shared__ float redout[8][8];

    const int tid  = threadIdx.x;
    const int wave = tid >> 6;      // 0..7
    const int lane = tid & 63;
    const int c16  = lane & 15;
    const int kq   = lane >> 4;     // 0..3
    const int row0 = blockIdx.x * 8;
    const int hid  = wave * 16 + c16;
    // compact h row read by this lane: pairs (c16, c16|2) broadcast
    const int hcr  = ((c16 >> 2) << 1) | (c16 & 1);

    // zero hbuf (h0 = 0): 2*8*128*2B = 4KB = 512 threads x 8B
    reinterpret_cast<unsigned long long*>(hbuf)[tid] = 0ull;

    // ---- weights -> register B-fragments (bf16) ----
    // wave w, gate tile n, col c16: logical gate G = n*128 + w*16 + c16
    // K: kt<4 -> w_ih, kt>=4 -> w_hh
    short8 bq[8][4];
#pragma unroll
    for (int kt = 0; kt < 8; ++kt) {
#pragma unroll
        for (int n = 0; n < 4; ++n) {
            const int G  = n * 128 + wave * 16 + c16;
            const int k0 = kt * 32 + kq * 8;
            const float* src = (kt < 4) ? (w_ih + G * 128 + k0)
                                        : (w_hh + G * 128 + (k0 - 128));
            f32x4 lo = *reinterpret_cast<const f32x4*>(src);
            f32x4 hi = *reinterpret_cast<const f32x4*>(src + 4);
            bq[kt][n] = pack8(lo, hi);
        }
    }
    float bias[4];
#pragma unroll
    for (int n = 0; n < 4; ++n) {
        const int G = n * 128 + wave * 16 + c16;
        bias[n] = b_ih[G] + b_hh[G];
    }

    // x staging: wave w owns batch row b=w; step-parity s at A-row r0 + 2s,
    // r0 = 4*(w>>1) + (w&1)
    const int r0s    = 4 * (wave >> 1) + (wave & 1);
    const int r1s    = r0s + 2;
    const int xwidx0 = (r0s * 128 + lane * 2) ^ ((r0s & 7) << 3);
    const int xwidx1 = (r1s * 128 + lane * 2) ^ ((r1s & 7) << 3);
    const float* xrow = x + (size_t)(row0 + wave) * T_STEPS * 128 + lane * 2;

    // prologue: stage steps 0,1 into xbuf[0]
    {
        f32x2 v0 = *reinterpret_cast<const f32x2*>(xrow);
        f32x2 v1 = *reinterpret_cast<const f32x2*>(xrow + 128);
        unsigned int p0 = cvt_pk_bf16(v0[0], v0[1]);
        unsigned int p1 = cvt_pk_bf16(v1[0], v1[1]);
        *reinterpret_cast<unsigned int*>(&xbuf[0][xwidx0]) = p0;
        *reinterpret_cast<unsigned int*>(&xbuf[0][xwidx1]) = p1;
    }

    // lane (c16,kq) owns batch rows {2kq+j}, j=0,1 -> compact h rows 2kq+j
    float cstate[2] = {0.f, 0.f};
    float accout[2] = {0.f, 0.f};
    float wlA = w_lin[hid];
    float wlB = w_lin[128 + hid];
    float wlA2, wlB2;
    f32x2 nx0, nx1;
    const int hwidx0 = ((2 * kq + 0) * 128 + hid) ^ ((2 * kq + 0) << 3);
    const int hwidx1 = ((2 * kq + 1) * 128 + hid) ^ ((2 * kq + 1) << 3);

    __syncthreads();  // zeros + x[0..1] staged

    for (int t = 0; t < T_STEPS; t += 4) {
        GROUP(t, 0);
        GROUP(t + 2, 1);
    }

    // ---- reduce accout over hid: 16-lane tree, then across waves ----
#pragma unroll
    for (int r = 0; r < 2; ++r) {
        float v = accout[r];
        v += __shfl_xor(v, 1);
        v += __shfl_xor(v, 2);
        v += __shfl_xor(v, 4);
        v += __shfl_xor(v, 8);
        if (c16 == 0) redout[wave][2 * kq + r] = v;  // batch row 2kq+r
    }
    __syncthreads();
    if (tid < 8) {
        float s = b_lin[0];
#pragma unroll
        for (int w = 0; w < 8; ++w) s += redout[w][tid];
        out[row0 + tid] = s;
    }
}

extern "C" void kernel_launch(void* const* d_in, const int* in_sizes, int n_in,
                              void* d_out, int out_size, void* d_ws, size_t ws_size,
                              hipStream_t stream) {
    const float* x     = (const float*)d_in[0];
    const float* w_ih  = (const float*)d_in[1];
    const float* w_hh  = (const float*)d_in[2];
    const float* b_ih  = (const float*)d_in[3];
    const float* b_hh  = (const float*)d_in[4];
    const float* w_lin = (const float*)d_in[5];
    const float* b_lin = (const float*)d_in[6];
    float* out = (float*)d_out;

    lstm_fused_kernel<<<256, 512, 0, stream>>>(x, w_ih, w_hh, b_ih, b_hh, w_lin, b_lin, out);
}